// Round 7
// baseline (36925.970 us; speedup 1.0000x reference)
//
#include <hip/hip_runtime.h>

// ShapeWeaverDecoder: 2-layer LSTM decoder, T=2048 steps, B=32, U=256.
// Round-7 = round-5/6 compute structure (proven absmax 0.0) + runtime-constructed
// co-XCD islands:
//   Each block reads its XCD via s_getreg(HW_REG_XCC_ID) [HW-verified, m09] and
//   takes a ticket from a per-XCD atomic counter. Ticket n on XCD x -> role
//   b = x*4 + n/8, g = n%8. With 1 block/CU (84KB LDS) each XCD hosts exactly
//   32 blocks, so every 8-block island is co-XCD BY CONSTRUCTION.
//   Exchange: fast ring (sc0, XCD-L2-coherent, ~200cy) polled 7/8 iterations;
//   safe ring (sc0 sc1, MALL) published always and polled every 8th iteration,
//   so correctness never depends on placement/XCC assumptions.
// Protocol (r3-r6): record = [h0..h3, chk], chk = ((((h0+h1)+h2)+h3)+tag) with
// bit-identical rounding on both sides; torn/stale/poison fails validation;
// ring depth 2; no fences; no ring reset (leftovers are bit-identical or fail).
// Roles permute across replays but all written VALUES are bit-identical ->
// deterministic output. tick[] is memset per launch.

#define TSTEPS 2048
#define NB     32
#define NTHR   512
#define RECF   8

typedef float f4 __attribute__((ext_vector_type(4)));

constexpr int SMEM_BYTES = 84 * 1024;   // force 1 block/CU (2x84KB > 160KB)
// float offsets into dynamic LDS
constexpr int OFF_H1   = 0;      // 256 floats (16B-aligned)
constexpr int OFF_H2   = 256;    // 256
constexpr int OFF_HIST = 512;    // 64
constexpr int OFF_Z1   = 576;    // 384 (stride-3 rows)
constexpr int OFF_Z2   = 960;    // 1152 (stride-9 rows; prologue scratch stride-33)
constexpr int OFF_G1   = 2112;   // 128
constexpr int OFF_G2   = 2240;   // 128
constexpr int OFF_X    = 2368;   // 2
constexpr int OFF_ROLE = 2372;   // 1 int slot

__device__ __forceinline__ float sigm(float x) { return 1.f / (1.f + expf(-x)); }

__device__ __forceinline__ float mk_chk(float a, float b, float c, float d, float t) {
  return __fadd_rn(__fadd_rn(__fadd_rn(__fadd_rn(a, b), c), d), t);
}
// fast: L1-bypass, L2-coherent (valid within an XCD)
__device__ __forceinline__ void load_rec_fast(const float* p, f4& a, float& chk) {
  asm volatile("global_load_dwordx4 %0, %2, off sc0\n\t"
               "global_load_dword %1, %2, off offset:16 sc0\n\t"
               "s_waitcnt vmcnt(0)"
               : "=&v"(a), "=&v"(chk) : "v"(p) : "memory");
}
// safe: MALL, device scope (proven r3-r6)
__device__ __forceinline__ void load_rec_safe(const float* p, f4& a, float& chk) {
  asm volatile("global_load_dwordx4 %0, %2, off sc0 sc1\n\t"
               "global_load_dword %1, %2, off offset:16 sc0 sc1\n\t"
               "s_waitcnt vmcnt(0)"
               : "=&v"(a), "=&v"(chk) : "v"(p) : "memory");
}
__device__ __forceinline__ void store_rec2(float* pf, float* ps, const f4& d, float chk) {
  asm volatile("global_store_dwordx4 %0, %2, off sc0\n\t"
               "global_store_dword %0, %3, off offset:16 sc0\n\t"
               "global_store_dwordx4 %1, %2, off sc0 sc1\n\t"
               "global_store_dword %1, %3, off offset:16 sc0 sc1"
               :: "v"(pf), "v"(ps), "v"(d), "v"(chk) : "memory");
}
__device__ __forceinline__ int recoff(int k, int b, int idx) {
  return (((k & 1) * NB + b) * 64 + idx) * RECF;
}

// Poll the 64 records of vector (k,b): lane l owns record l. Fast (XCD-L2) ring
// 7/8 iterations, safe (MALL) ring every 8th. Bounded -> terminates on bugs.
__device__ __forceinline__ bool poll64(const float* ringF, const float* ringS,
                                       int k, int b, float tag, int lane,
                                       f4& d, bool ok) {
  if (!ok) return false;
  const int off = recoff(k, b, lane);
  const float* pf = ringF + off;
  const float* ps = ringS + off;
  bool v = false;
  int it = 0;
  while (!__all(v)) {
    if (!v) {
      f4 a; float cc;
      if ((it & 7) == 7) load_rec_safe(ps, a, cc);
      else               load_rec_fast(pf, a, cc);
      if (__float_as_uint(cc) == __float_as_uint(mk_chk(a.x, a.y, a.z, a.w, tag))) {
        d = a; v = true;
      }
    }
    if (++it > (1 << 15)) return false;
    if (it > 128) __builtin_amdgcn_s_sleep(1);
  }
  return true;
}

__global__ __launch_bounds__(NTHR) void swd_kernel(
    const float* __restrict__ ctx, const float* __restrict__ Wc, const float* __restrict__ bc,
    const float* __restrict__ K1, const float* __restrict__ R1, const float* __restrict__ b1,
    const float* __restrict__ K2, const float* __restrict__ R2, const float* __restrict__ b2,
    const float* __restrict__ Wo, const float* __restrict__ bo,
    float* __restrict__ dout, int* __restrict__ tick,
    float* __restrict__ ring1f, float* __restrict__ ring1s,
    float* __restrict__ ring2f, float* __restrict__ ring2s)
{
  extern __shared__ float sm[];
  float* h1buf = sm + OFF_H1;
  float* h2buf = sm + OFF_H2;
  float* hist  = sm + OFF_HIST;
  float* zbuf1 = sm + OFF_Z1;
  float* zbuf2 = sm + OFF_Z2;
  float* gbuf1 = sm + OFF_G1;
  float* gbuf2 = sm + OFF_G2;
  float* xbuf  = sm + OFF_X;

  const int t = threadIdx.x;

  // ---- runtime role assignment: co-XCD islands by construction ----
  int xcc;
  asm volatile("s_getreg_b32 %0, hwreg(HW_REG_XCC_ID)" : "=s"(xcc));
  xcc &= 7;
  if (t == 0) ((int*)sm)[OFF_ROLE] = atomicAdd(tick + xcc, 1);
  __syncthreads();
  const int ticket = ((int*)sm)[OFF_ROLE];
  const int b = (xcc * 4 + (ticket >> 3)) & 31;  // batch (island id)
  const int g = ticket & 7;                      // unit slice within island

  const int lane = t & 63;
  const bool w0  = (t < 64);
  const bool w7  = (t >= 448);
  const int col  = t & 127;          // local gate-col
  const int khq  = t >> 7;           // 0..3
  const int kh   = khq & 1;
  const int q    = col >> 5;         // gate (i,f,g,o)
  const int j    = col & 31;         // unit within slice
  const int kcol = q * 256 + 32 * g + j;   // keras gate-major column

  // ---- weights into VGPRs (uniform 192 regs/thread) ----
  const float* baseA = (t < 256) ? R1 : K2;
  float wA[128], wB[64];
  #pragma unroll
  for (int m = 0; m < 128; ++m) wA[m] = baseA[(kh * 128 + m) * 1024 + kcol];
  #pragma unroll
  for (int m = 0; m < 64; ++m) wB[m] = R2[(khq * 64 + m) * 1024 + kcol];

  float k1a = 0.f, k1b = 0.f, bb1 = 0.f, bb2 = 0.f;
  if (t < 128)      { k1a = K1[kcol]; k1b = K1[1024 + kcol]; bb1 = b1[kcol]; }
  else if (t < 256) { bb2 = b2[kcol]; }
  float wo0[4], wo1[4], bo0 = 0.f, bo1 = 0.f;
  if (w7) {
    #pragma unroll
    for (int m = 0; m < 4; ++m) {
      wo0[m] = Wo[(4 * lane + m) * 2];
      wo1[m] = Wo[(4 * lane + m) * 2 + 1];
    }
    bo0 = bo[0]; bo1 = bo[1];
  }

  // ---- prologue: h1[0] slice = relu(ctx @ Wc + bc), publish tag 0, stage ----
  {
    const int jj = t & 31, kc = t >> 5;      // 16 chunks of 32
    float p = 0.f;
    #pragma unroll
    for (int m = 0; m < 32; ++m)
      p = fmaf(ctx[b * 512 + kc * 32 + m], Wc[(kc * 32 + m) * 256 + 32 * g + jj], p);
    zbuf2[kc * 33 + jj] = p;
  }
  if (t == 0) { xbuf[0] = 0.5f; xbuf[1] = 0.5f; }
  if (t < 256) h2buf[t] = 0.f;
  __syncthreads();

  bool ok = true;
  float c1 = 0.f, c2 = 0.f, hn = 0.f;
  if (t < 32) {
    float sum = bc[32 * g + t];
    #pragma unroll
    for (int kc = 0; kc < 16; ++kc) sum += zbuf2[kc * 33 + t];
    hn = fmaxf(sum, 0.f);
  }
  if (w0) {
    const float h0  = __shfl(hn, (4 * lane + 0) & 31), h1v = __shfl(hn, (4 * lane + 1) & 31),
                h2v = __shfl(hn, (4 * lane + 2) & 31), h3v = __shfl(hn, (4 * lane + 3) & 31);
    if (lane < 8) {
      f4 dd; dd.x = h0; dd.y = h1v; dd.z = h2v; dd.w = h3v;
      const int off = recoff(0, b, g * 8 + lane);
      store_rec2(ring1f + off, ring1s + off, dd, mk_chk(h0, h1v, h2v, h3v, 0.f));
    }
  }
  if (w7) {
    f4 d;
    ok = poll64(ring1f, ring1s, 0, b, 0.f, lane, d, ok);
    *(f4*)(h1buf + 4 * lane) = d;
  }
  __syncthreads();

  // ==================== main loop (structure proven in r5/r6) ====================
  for (int s = 0; s < TSTEPS; ++s) {
    // P1: R1 half-dots on h1[s] (waves 0-3)  ||  P2: wave 7 polls h2[s] -> x
    if (t < 256) {
      float a0 = 0.f, a1 = 0.f, a2 = 0.f, a3 = 0.f;
      const f4* hp = (const f4*)(h1buf + kh * 128);
      #pragma unroll
      for (int m = 0; m < 32; ++m) {
        const f4 hv = hp[m];
        a0 = fmaf(wA[4 * m + 0], hv.x, a0);
        a1 = fmaf(wA[4 * m + 1], hv.y, a1);
        a2 = fmaf(wA[4 * m + 2], hv.z, a2);
        a3 = fmaf(wA[4 * m + 3], hv.w, a3);
      }
      zbuf1[col * 3 + kh] = (a0 + a1) + (a2 + a3);
    } else if (w7 && s > 0) {
      f4 gg;
      ok = poll64(ring2f, ring2s, s, b, (float)s, lane, gg, ok);
      *(f4*)(h2buf + 4 * lane) = gg;                 // lane l holds units 4l..4l+3
      float po0 = gg.x * wo0[0] + gg.y * wo0[1] + gg.z * wo0[2] + gg.w * wo0[3];
      float po1 = gg.x * wo1[0] + gg.y * wo1[1] + gg.z * wo1[2] + gg.w * wo1[3];
      #pragma unroll
      for (int dd = 1; dd < 64; dd <<= 1) { po0 += __shfl_xor(po0, dd); po1 += __shfl_xor(po1, dd); }
      const float x0 = sigm(po0 + bo0), x1 = sigm(po1 + bo1);
      if (lane == 0) {
        xbuf[0] = x0; xbuf[1] = x1;
        if (g == 0) { hist[((s - 1) & 31) * 2] = x0; hist[((s - 1) & 31) * 2 + 1] = x1; }
      }
    }
    __syncthreads();  // B1

    // P3: z1 finalize (t<128, critical), then R2 quarter-dots (all threads)
    if (t < 128) {
      const float z = (zbuf1[3 * t] + zbuf1[3 * t + 1]) + xbuf[0] * k1a + xbuf[1] * k1b + bb1;
      gbuf1[t] = (q == 2) ? tanhf(z) : sigm(z);
    }
    {
      float a0 = 0.f, a1 = 0.f, a2 = 0.f, a3 = 0.f;
      const f4* hp = (const f4*)(h2buf + khq * 64);
      #pragma unroll
      for (int m = 0; m < 16; ++m) {
        const f4 hv = hp[m];
        a0 = fmaf(wB[4 * m + 0], hv.x, a0);
        a1 = fmaf(wB[4 * m + 1], hv.y, a1);
        a2 = fmaf(wB[4 * m + 2], hv.z, a2);
        a3 = fmaf(wB[4 * m + 3], hv.w, a3);
      }
      zbuf2[col * 9 + khq] = (a0 + a1) + (a2 + a3);
    }
    if (w7 && g == 0 && s >= 32 && (s & 31) == 0 && lane < 16) {   // batched dout flush
      const f4 v = *(const f4*)(hist + 4 * lane);
      *(f4*)(dout + (b * TSTEPS + (s - 32)) * 2 + 4 * lane) = v;
    }
    __syncthreads();  // C

    // P4: h1 update + publish (wave 0)  ||  P5: wave 7 polls h1[s+1]
    if (t < 32) {
      const float gi = gbuf1[t], gf = gbuf1[32 + t], gG = gbuf1[64 + t], gO = gbuf1[96 + t];
      const float cn = gf * c1 + gi * gG;
      c1 = cn;
      hn = gO * tanhf(cn);
    }
    if (w0) {
      const float h0  = __shfl(hn, (4 * lane + 0) & 31), h1v = __shfl(hn, (4 * lane + 1) & 31),
                  h2v = __shfl(hn, (4 * lane + 2) & 31), h3v = __shfl(hn, (4 * lane + 3) & 31);
      if (lane < 8) {
        f4 dd; dd.x = h0; dd.y = h1v; dd.z = h2v; dd.w = h3v;
        const int off = recoff(s + 1, b, g * 8 + lane);
        store_rec2(ring1f + off, ring1s + off, dd, mk_chk(h0, h1v, h2v, h3v, (float)(s + 1)));
      }
    }
    if (w7) {
      f4 d;
      ok = poll64(ring1f, ring1s, s + 1, b, (float)(s + 1), lane, d, ok);
      *(f4*)(h1buf + 4 * lane) = d;
    }
    __syncthreads();  // D

    // P6: K2 half-dots on h1[s+1] (waves 4-7)
    if (t >= 256) {
      float a0 = 0.f, a1 = 0.f, a2 = 0.f, a3 = 0.f;
      const f4* hp = (const f4*)(h1buf + kh * 128);
      #pragma unroll
      for (int m = 0; m < 32; ++m) {
        const f4 hv = hp[m];
        a0 = fmaf(wA[4 * m + 0], hv.x, a0);
        a1 = fmaf(wA[4 * m + 1], hv.y, a1);
        a2 = fmaf(wA[4 * m + 2], hv.z, a2);
        a3 = fmaf(wA[4 * m + 3], hv.w, a3);
      }
      zbuf2[col * 9 + 4 + kh] = (a0 + a1) + (a2 + a3);
    }
    __syncthreads();  // E

    // P7: z2 finalize (waves 2-3)
    if (t >= 128 && t < 256) {
      const int c = t - 128;
      const float z = ((zbuf2[c * 9 + 0] + zbuf2[c * 9 + 1]) + (zbuf2[c * 9 + 2] + zbuf2[c * 9 + 3]))
                    + (zbuf2[c * 9 + 4] + zbuf2[c * 9 + 5]) + bb2;
      gbuf2[c] = (q == 2) ? tanhf(z) : sigm(z);
    }
    __syncthreads();  // F

    // P8: h2 update + publish (wave 0, lanes 32-63)
    if (t >= 32 && t < 64) {
      const int jj = t - 32;
      const float gi = gbuf2[jj], gf = gbuf2[32 + jj], gG = gbuf2[64 + jj], gO = gbuf2[96 + jj];
      const float cn = gf * c2 + gi * gG;
      c2 = cn;
      hn = gO * tanhf(cn);
    }
    if (w0) {
      const float h0  = __shfl(hn, 32 + ((4 * lane + 0) & 31)), h1v = __shfl(hn, 32 + ((4 * lane + 1) & 31)),
                  h2v = __shfl(hn, 32 + ((4 * lane + 2) & 31)), h3v = __shfl(hn, 32 + ((4 * lane + 3) & 31));
      if (lane >= 32 && lane < 40) {
        f4 dd; dd.x = h0; dd.y = h1v; dd.z = h2v; dd.w = h3v;
        const int off = recoff(s + 1, b, g * 8 + (lane - 32));
        store_rec2(ring2f + off, ring2s + off, dd, mk_chk(h0, h1v, h2v, h3v, (float)(s + 1)));
      }
    }
    // no barrier: exchange is via global memory; next step's B1 covers LDS ordering
  }

  // ---- epilogue: out[T-1] from h2[T] (island's g==0 block), final flush ----
  if (g == 0 && w7) {
    f4 gg;
    ok = poll64(ring2f, ring2s, TSTEPS, b, (float)TSTEPS, lane, gg, ok);
    float po0 = gg.x * wo0[0] + gg.y * wo0[1] + gg.z * wo0[2] + gg.w * wo0[3];
    float po1 = gg.x * wo1[0] + gg.y * wo1[1] + gg.z * wo1[2] + gg.w * wo1[3];
    #pragma unroll
    for (int dd = 1; dd < 64; dd <<= 1) { po0 += __shfl_xor(po0, dd); po1 += __shfl_xor(po1, dd); }
    if (lane == 0) { hist[62] = sigm(po0 + bo0); hist[63] = sigm(po1 + bo1); }
    if (lane < 16) {
      const f4 v = *(const f4*)(hist + 4 * lane);
      *(f4*)(dout + (b * TSTEPS + TSTEPS - 32) * 2 + 4 * lane) = v;
    }
  }
  (void)ok;
}

extern "C" void kernel_launch(void* const* d_in, const int* in_sizes, int n_in,
                              void* d_out, int out_size, void* d_ws, size_t ws_size,
                              hipStream_t stream) {
  (void)in_sizes; (void)n_in; (void)out_size; (void)ws_size;
  const float* ctx = (const float*)d_in[0];
  const float* Wc  = (const float*)d_in[1];
  const float* bc  = (const float*)d_in[2];
  const float* K1  = (const float*)d_in[3];
  const float* R1  = (const float*)d_in[4];
  const float* b1  = (const float*)d_in[5];
  const float* K2  = (const float*)d_in[6];
  const float* R2  = (const float*)d_in[7];
  const float* b2  = (const float*)d_in[8];
  const float* Wo  = (const float*)d_in[9];
  const float* bo  = (const float*)d_in[10];

  const int RING = 2 * NB * 64 * RECF;           // 32768 floats = 128 KiB
  int*   tick   = (int*)d_ws;                    // [8] per-XCD ticket counters
  float* base   = (float*)((char*)d_ws + 256);
  float* ring1f = base;                          // fast (XCD-L2) rings
  float* ring2f = ring1f + RING;
  float* ring1s = ring2f + RING;                 // safe (MALL) rings
  float* ring2s = ring1s + RING;                 // total 512 KiB + 256 B
  // Rings need no reset (self-validating records). Tickets must start at 0.
  hipMemsetAsync(d_ws, 0, 8 * sizeof(int), stream);

  hipFuncSetAttribute((const void*)swd_kernel,
                      hipFuncAttributeMaxDynamicSharedMemorySize, SMEM_BYTES);
  swd_kernel<<<dim3(256), dim3(NTHR), SMEM_BYTES, stream>>>(
      ctx, Wc, bc, K1, R1, b1, K2, R2, b2, Wo, bo,
      (float*)d_out, tick, ring1f, ring1s, ring2f, ring2s);
}

// Round 8
// 35574.051 us; speedup vs baseline: 1.0380x; 1.0380x over previous
//
#include <hip/hip_runtime.h>

// ShapeWeaverDecoder: 2-layer LSTM decoder, T=2048 steps, B=32, U=256.
// Round-8 = round-7 structure with the REGISTER SPILL fixed:
//   r5-r7 declared 192 weight floats/thread but compiled at VGPR_Count=128 ->
//   weights spilled to scratch -> every step re-read ~393KB/block from memory
//   (the round-0 "dead design"). Fix:
//     - __launch_bounds__(512, 2): allows 256 VGPRs/thread
//     - R2 moved to LDS (132KB, [512][66] padded layout, 2 lanes/bank = free),
//       loaded once; per-thread regs = wA[128] + working ~ 180 -> no spill.
// Everything else (islands via XCC_ID tickets, checksum records, dual
// fast(sc0)/safe(sc0 sc1) rings, ring depth 2, no resets) proven r5-r7,
// absmax 0.0. Poll backoff added (s_sleep after 4 iters) to decongest.

#define TSTEPS 2048
#define NB     32
#define NTHR   512
#define RECF   8

typedef float f4 __attribute__((ext_vector_type(4)));

// float offsets into dynamic LDS
constexpr int OFF_R2L  = 0;          // 512*66 floats (R2 slice, padded)
constexpr int OFF_H1   = 33792;      // 256 (16B-aligned)
constexpr int OFF_H2   = 34048;      // 256
constexpr int OFF_HIST = 34304;      // 64
constexpr int OFF_Z1   = 34368;      // 384 (stride-3 rows)
constexpr int OFF_Z2   = 34752;      // 1152 (stride-9 rows; prologue scratch stride-33)
constexpr int OFF_G1   = 35904;      // 128
constexpr int OFF_G2   = 36032;      // 128
constexpr int OFF_X    = 36160;      // 2
constexpr int OFF_ROLE = 36162;      // 1 int slot
constexpr int SMEM_BYTES = 36164 * 4;   // 144656 B -> 1 block/CU (2x > 160KB)

__device__ __forceinline__ float sigm(float x) { return 1.f / (1.f + expf(-x)); }

__device__ __forceinline__ float mk_chk(float a, float b, float c, float d, float t) {
  return __fadd_rn(__fadd_rn(__fadd_rn(__fadd_rn(a, b), c), d), t);
}
// fast: L1-bypass, L2-coherent (valid within an XCD)
__device__ __forceinline__ void load_rec_fast(const float* p, f4& a, float& chk) {
  asm volatile("global_load_dwordx4 %0, %2, off sc0\n\t"
               "global_load_dword %1, %2, off offset:16 sc0\n\t"
               "s_waitcnt vmcnt(0)"
               : "=&v"(a), "=&v"(chk) : "v"(p) : "memory");
}
// safe: MALL, device scope (proven r3-r7)
__device__ __forceinline__ void load_rec_safe(const float* p, f4& a, float& chk) {
  asm volatile("global_load_dwordx4 %0, %2, off sc0 sc1\n\t"
               "global_load_dword %1, %2, off offset:16 sc0 sc1\n\t"
               "s_waitcnt vmcnt(0)"
               : "=&v"(a), "=&v"(chk) : "v"(p) : "memory");
}
__device__ __forceinline__ void store_rec2(float* pf, float* ps, const f4& d, float chk) {
  asm volatile("global_store_dwordx4 %0, %2, off sc0\n\t"
               "global_store_dword %0, %3, off offset:16 sc0\n\t"
               "global_store_dwordx4 %1, %2, off sc0 sc1\n\t"
               "global_store_dword %1, %3, off offset:16 sc0 sc1"
               :: "v"(pf), "v"(ps), "v"(d), "v"(chk) : "memory");
}
__device__ __forceinline__ int recoff(int k, int b, int idx) {
  return (((k & 1) * NB + b) * 64 + idx) * RECF;
}

// Poll the 64 records of vector (k,b): lane l owns record l. Fast (XCD-L2) ring
// with safe (MALL) read every 4th iteration; backoff after 4 iters. Bounded.
__device__ __forceinline__ bool poll64(const float* ringF, const float* ringS,
                                       int k, int b, float tag, int lane,
                                       f4& d, bool ok) {
  if (!ok) return false;
  const int off = recoff(k, b, lane);
  const float* pf = ringF + off;
  const float* ps = ringS + off;
  bool v = false;
  int it = 0;
  while (!__all(v)) {
    if (!v) {
      f4 a; float cc;
      if ((it & 3) == 3) load_rec_safe(ps, a, cc);
      else               load_rec_fast(pf, a, cc);
      if (__float_as_uint(cc) == __float_as_uint(mk_chk(a.x, a.y, a.z, a.w, tag))) {
        d = a; v = true;
      }
    }
    if (++it > (1 << 15)) return false;
    if (it > 64) __builtin_amdgcn_s_sleep(16);
    else if (it > 4) __builtin_amdgcn_s_sleep(2);
  }
  return true;
}

__global__ __launch_bounds__(NTHR, 2) void swd_kernel(
    const float* __restrict__ ctx, const float* __restrict__ Wc, const float* __restrict__ bc,
    const float* __restrict__ K1, const float* __restrict__ R1, const float* __restrict__ b1,
    const float* __restrict__ K2, const float* __restrict__ R2, const float* __restrict__ b2,
    const float* __restrict__ Wo, const float* __restrict__ bo,
    float* __restrict__ dout, int* __restrict__ tick,
    float* __restrict__ ring1f, float* __restrict__ ring1s,
    float* __restrict__ ring2f, float* __restrict__ ring2s)
{
  extern __shared__ float sm[];
  float* r2l   = sm + OFF_R2L;
  float* h1buf = sm + OFF_H1;
  float* h2buf = sm + OFF_H2;
  float* hist  = sm + OFF_HIST;
  float* zbuf1 = sm + OFF_Z1;
  float* zbuf2 = sm + OFF_Z2;
  float* gbuf1 = sm + OFF_G1;
  float* gbuf2 = sm + OFF_G2;
  float* xbuf  = sm + OFF_X;

  const int t = threadIdx.x;

  // ---- runtime role assignment: co-XCD islands by construction ----
  int xcc;
  asm volatile("s_getreg_b32 %0, hwreg(HW_REG_XCC_ID)" : "=s"(xcc));
  xcc &= 7;
  if (t == 0) ((int*)sm)[OFF_ROLE] = atomicAdd(tick + xcc, 1);
  __syncthreads();
  const int ticket = ((int*)sm)[OFF_ROLE];
  const int b = (xcc * 4 + (ticket >> 3)) & 31;  // batch (island id)
  const int g = ticket & 7;                      // unit slice within island

  const int lane = t & 63;
  const bool w0  = (t < 64);
  const bool w7  = (t >= 448);
  const int col  = t & 127;          // local gate-col
  const int khq  = t >> 7;           // 0..3
  const int kh   = khq & 1;
  const int q    = col >> 5;         // gate (i,f,g,o)
  const int j    = col & 31;         // unit within slice
  const int kcol = q * 256 + 32 * g + j;   // keras gate-major column

  // ---- weights: wA in VGPRs (128/thread), R2 slice into LDS (one-time) ----
  const float* baseA = (t < 256) ? R1 : K2;
  float wA[128];
  #pragma unroll
  for (int m = 0; m < 128; ++m) wA[m] = baseA[(kh * 128 + m) * 1024 + kcol];
  {
    float* dst = r2l + (col * 4 + khq) * 66;
    #pragma unroll
    for (int m = 0; m < 64; ++m) dst[m] = R2[(khq * 64 + m) * 1024 + kcol];
  }

  float k1a = 0.f, k1b = 0.f, bb1 = 0.f, bb2 = 0.f;
  if (t < 128)      { k1a = K1[kcol]; k1b = K1[1024 + kcol]; bb1 = b1[kcol]; }
  else if (t < 256) { bb2 = b2[kcol]; }
  float wo0[4], wo1[4], bo0 = 0.f, bo1 = 0.f;
  if (w7) {
    #pragma unroll
    for (int m = 0; m < 4; ++m) {
      wo0[m] = Wo[(4 * lane + m) * 2];
      wo1[m] = Wo[(4 * lane + m) * 2 + 1];
    }
    bo0 = bo[0]; bo1 = bo[1];
  }

  // ---- prologue: h1[0] slice = relu(ctx @ Wc + bc), publish tag 0, stage ----
  {
    const int jj = t & 31, kc = t >> 5;      // 16 chunks of 32
    float p = 0.f;
    #pragma unroll
    for (int m = 0; m < 32; ++m)
      p = fmaf(ctx[b * 512 + kc * 32 + m], Wc[(kc * 32 + m) * 256 + 32 * g + jj], p);
    zbuf2[kc * 33 + jj] = p;
  }
  if (t == 0) { xbuf[0] = 0.5f; xbuf[1] = 0.5f; }
  if (t < 256) h2buf[t] = 0.f;
  __syncthreads();

  bool ok = true;
  float c1 = 0.f, c2 = 0.f, hn = 0.f;
  if (t < 32) {
    float sum = bc[32 * g + t];
    #pragma unroll
    for (int kc = 0; kc < 16; ++kc) sum += zbuf2[kc * 33 + t];
    hn = fmaxf(sum, 0.f);
  }
  if (w0) {
    const float h0  = __shfl(hn, (4 * lane + 0) & 31), h1v = __shfl(hn, (4 * lane + 1) & 31),
                h2v = __shfl(hn, (4 * lane + 2) & 31), h3v = __shfl(hn, (4 * lane + 3) & 31);
    if (lane < 8) {
      f4 dd; dd.x = h0; dd.y = h1v; dd.z = h2v; dd.w = h3v;
      const int off = recoff(0, b, g * 8 + lane);
      store_rec2(ring1f + off, ring1s + off, dd, mk_chk(h0, h1v, h2v, h3v, 0.f));
    }
  }
  if (w7) {
    f4 d;
    ok = poll64(ring1f, ring1s, 0, b, 0.f, lane, d, ok);
    *(f4*)(h1buf + 4 * lane) = d;
  }
  __syncthreads();

  // ==================== main loop (structure proven in r5-r7) ====================
  for (int s = 0; s < TSTEPS; ++s) {
    // P1: R1 half-dots on h1[s] (waves 0-3)  ||  P2: wave 7 polls h2[s] -> x
    if (t < 256) {
      float a0 = 0.f, a1 = 0.f, a2 = 0.f, a3 = 0.f;
      const f4* hp = (const f4*)(h1buf + kh * 128);
      #pragma unroll
      for (int m = 0; m < 32; ++m) {
        const f4 hv = hp[m];
        a0 = fmaf(wA[4 * m + 0], hv.x, a0);
        a1 = fmaf(wA[4 * m + 1], hv.y, a1);
        a2 = fmaf(wA[4 * m + 2], hv.z, a2);
        a3 = fmaf(wA[4 * m + 3], hv.w, a3);
      }
      zbuf1[col * 3 + kh] = (a0 + a1) + (a2 + a3);
    } else if (w7 && s > 0) {
      f4 gg;
      ok = poll64(ring2f, ring2s, s, b, (float)s, lane, gg, ok);
      *(f4*)(h2buf + 4 * lane) = gg;                 // lane l holds units 4l..4l+3
      float po0 = gg.x * wo0[0] + gg.y * wo0[1] + gg.z * wo0[2] + gg.w * wo0[3];
      float po1 = gg.x * wo1[0] + gg.y * wo1[1] + gg.z * wo1[2] + gg.w * wo1[3];
      #pragma unroll
      for (int dd = 1; dd < 64; dd <<= 1) { po0 += __shfl_xor(po0, dd); po1 += __shfl_xor(po1, dd); }
      const float x0 = sigm(po0 + bo0), x1 = sigm(po1 + bo1);
      if (lane == 0) {
        xbuf[0] = x0; xbuf[1] = x1;
        if (g == 0) { hist[((s - 1) & 31) * 2] = x0; hist[((s - 1) & 31) * 2 + 1] = x1; }
      }
    }
    __syncthreads();  // B1

    // P3: z1 finalize (t<128, critical), then R2 quarter-dots (all threads, R2 from LDS)
    if (t < 128) {
      const float z = (zbuf1[3 * t] + zbuf1[3 * t + 1]) + xbuf[0] * k1a + xbuf[1] * k1b + bb1;
      gbuf1[t] = (q == 2) ? tanhf(z) : sigm(z);
    }
    {
      float a0 = 0.f, a1 = 0.f, a2 = 0.f, a3 = 0.f;
      const f4* hp = (const f4*)(h2buf + khq * 64);
      const float* wp = r2l + (col * 4 + khq) * 66;
      #pragma unroll
      for (int m = 0; m < 16; ++m) {
        const f4 hv = hp[m];
        const f4 wv = *(const f4*)(wp + 4 * m);
        a0 = fmaf(wv.x, hv.x, a0);
        a1 = fmaf(wv.y, hv.y, a1);
        a2 = fmaf(wv.z, hv.z, a2);
        a3 = fmaf(wv.w, hv.w, a3);
      }
      zbuf2[col * 9 + khq] = (a0 + a1) + (a2 + a3);
    }
    if (w7 && g == 0 && s >= 32 && (s & 31) == 0 && lane < 16) {   // batched dout flush
      const f4 v = *(const f4*)(hist + 4 * lane);
      *(f4*)(dout + (b * TSTEPS + (s - 32)) * 2 + 4 * lane) = v;
    }
    __syncthreads();  // C

    // P4: h1 update + publish (wave 0)  ||  P5: wave 7 polls h1[s+1]
    if (t < 32) {
      const float gi = gbuf1[t], gf = gbuf1[32 + t], gG = gbuf1[64 + t], gO = gbuf1[96 + t];
      const float cn = gf * c1 + gi * gG;
      c1 = cn;
      hn = gO * tanhf(cn);
    }
    if (w0) {
      const float h0  = __shfl(hn, (4 * lane + 0) & 31), h1v = __shfl(hn, (4 * lane + 1) & 31),
                  h2v = __shfl(hn, (4 * lane + 2) & 31), h3v = __shfl(hn, (4 * lane + 3) & 31);
      if (lane < 8) {
        f4 dd; dd.x = h0; dd.y = h1v; dd.z = h2v; dd.w = h3v;
        const int off = recoff(s + 1, b, g * 8 + lane);
        store_rec2(ring1f + off, ring1s + off, dd, mk_chk(h0, h1v, h2v, h3v, (float)(s + 1)));
      }
    }
    if (w7) {
      f4 d;
      ok = poll64(ring1f, ring1s, s + 1, b, (float)(s + 1), lane, d, ok);
      *(f4*)(h1buf + 4 * lane) = d;
    }
    __syncthreads();  // D

    // P6: K2 half-dots on h1[s+1] (waves 4-7)
    if (t >= 256) {
      float a0 = 0.f, a1 = 0.f, a2 = 0.f, a3 = 0.f;
      const f4* hp = (const f4*)(h1buf + kh * 128);
      #pragma unroll
      for (int m = 0; m < 32; ++m) {
        const f4 hv = hp[m];
        a0 = fmaf(wA[4 * m + 0], hv.x, a0);
        a1 = fmaf(wA[4 * m + 1], hv.y, a1);
        a2 = fmaf(wA[4 * m + 2], hv.z, a2);
        a3 = fmaf(wA[4 * m + 3], hv.w, a3);
      }
      zbuf2[col * 9 + 4 + kh] = (a0 + a1) + (a2 + a3);
    }
    __syncthreads();  // E

    // P7: z2 finalize (waves 2-3)
    if (t >= 128 && t < 256) {
      const int c = t - 128;
      const float z = ((zbuf2[c * 9 + 0] + zbuf2[c * 9 + 1]) + (zbuf2[c * 9 + 2] + zbuf2[c * 9 + 3]))
                    + (zbuf2[c * 9 + 4] + zbuf2[c * 9 + 5]) + bb2;
      gbuf2[c] = (q == 2) ? tanhf(z) : sigm(z);
    }
    __syncthreads();  // F

    // P8: h2 update + publish (wave 0, lanes 32-63)
    if (t >= 32 && t < 64) {
      const int jj = t - 32;
      const float gi = gbuf2[jj], gf = gbuf2[32 + jj], gG = gbuf2[64 + jj], gO = gbuf2[96 + jj];
      const float cn = gf * c2 + gi * gG;
      c2 = cn;
      hn = gO * tanhf(cn);
    }
    if (w0) {
      const float h0  = __shfl(hn, 32 + ((4 * lane + 0) & 31)), h1v = __shfl(hn, 32 + ((4 * lane + 1) & 31)),
                  h2v = __shfl(hn, 32 + ((4 * lane + 2) & 31)), h3v = __shfl(hn, 32 + ((4 * lane + 3) & 31));
      if (lane >= 32 && lane < 40) {
        f4 dd; dd.x = h0; dd.y = h1v; dd.z = h2v; dd.w = h3v;
        const int off = recoff(s + 1, b, g * 8 + (lane - 32));
        store_rec2(ring2f + off, ring2s + off, dd, mk_chk(h0, h1v, h2v, h3v, (float)(s + 1)));
      }
    }
    // no barrier: exchange is via global memory; next step's B1 covers LDS ordering
  }

  // ---- epilogue: out[T-1] from h2[T] (island's g==0 block), final flush ----
  if (g == 0 && w7) {
    f4 gg;
    ok = poll64(ring2f, ring2s, TSTEPS, b, (float)TSTEPS, lane, gg, ok);
    float po0 = gg.x * wo0[0] + gg.y * wo0[1] + gg.z * wo0[2] + gg.w * wo0[3];
    float po1 = gg.x * wo1[0] + gg.y * wo1[1] + gg.z * wo1[2] + gg.w * wo1[3];
    #pragma unroll
    for (int dd = 1; dd < 64; dd <<= 1) { po0 += __shfl_xor(po0, dd); po1 += __shfl_xor(po1, dd); }
    if (lane == 0) { hist[62] = sigm(po0 + bo0); hist[63] = sigm(po1 + bo1); }
    if (lane < 16) {
      const f4 v = *(const f4*)(hist + 4 * lane);
      *(f4*)(dout + (b * TSTEPS + TSTEPS - 32) * 2 + 4 * lane) = v;
    }
  }
  (void)ok;
}

extern "C" void kernel_launch(void* const* d_in, const int* in_sizes, int n_in,
                              void* d_out, int out_size, void* d_ws, size_t ws_size,
                              hipStream_t stream) {
  (void)in_sizes; (void)n_in; (void)out_size; (void)ws_size;
  const float* ctx = (const float*)d_in[0];
  const float* Wc  = (const float*)d_in[1];
  const float* bc  = (const float*)d_in[2];
  const float* K1  = (const float*)d_in[3];
  const float* R1  = (const float*)d_in[4];
  const float* b1  = (const float*)d_in[5];
  const float* K2  = (const float*)d_in[6];
  const float* R2  = (const float*)d_in[7];
  const float* b2  = (const float*)d_in[8];
  const float* Wo  = (const float*)d_in[9];
  const float* bo  = (const float*)d_in[10];

  const int RING = 2 * NB * 64 * RECF;           // 32768 floats = 128 KiB
  int*   tick   = (int*)d_ws;                    // [8] per-XCD ticket counters
  float* base   = (float*)((char*)d_ws + 256);
  float* ring1f = base;                          // fast (XCD-L2) rings
  float* ring2f = ring1f + RING;
  float* ring1s = ring2f + RING;                 // safe (MALL) rings
  float* ring2s = ring1s + RING;                 // total 512 KiB + 256 B
  // Rings need no reset (self-validating records). Tickets must start at 0.
  hipMemsetAsync(d_ws, 0, 8 * sizeof(int), stream);

  hipFuncSetAttribute((const void*)swd_kernel,
                      hipFuncAttributeMaxDynamicSharedMemorySize, SMEM_BYTES);
  swd_kernel<<<dim3(256), dim3(NTHR), SMEM_BYTES, stream>>>(
      ctx, Wc, bc, K1, R1, b1, K2, R2, b2, Wo, bo,
      (float*)d_out, tick, ring1f, ring1s, ring2f, ring2s);
}

// Round 9
// 29407.849 us; speedup vs baseline: 1.2557x; 1.2097x over previous
//
#include <hip/hip_runtime.h>

// ShapeWeaverDecoder: 2-layer LSTM decoder, T=2048 sequential steps, B=32, U=256.
// Round-9 = round-2 (champion, 26.3ms, absmax 0.0) with ONE change: the L2
// blocks' R2 weights move from per-thread registers (which spilled: needed
// ~160 regs at VGPR_Count=112) to a block-shared LDS slice [64 rows][stride 66]
// loaded once. L2 per-thread regs drop to ~105 -> no spill. Everything else
// (topology, flag+ring protocol, schedule, lane maps) is byte-identical to r2.
//   grid = 256 blocks x 512 threads (8 waves), 84KB dynamic LDS => 1 block/CU.
//   blocks [0,128):  layer-1 slices (W1 in 64 VGPRs/lane) + output dense.
//   blocks [128,256): layer-2 slices (K2 in 64 VGPRs/lane, R2 in LDS).
// h exchange across blocks through MALL (agent-scope atomics) via 4-deep rings
// in d_ws with monotonic per-(batch,slice) flags. No __syncthreads in the main
// loop (all LDS working buffers are wave-private; R2 LDS is read-only there).

#define TSTEPS 2048
#define UNITS  256
#define NB     32
#define NSL    64
#define NTHR   512

constexpr int CH   = 72;            // chunk stride (floats) in LDS staging
constexpr int VECF = 4 * CH;        // 288 floats per staged 256-vector
constexpr int BUFW = 2 * 2 * VECF;  // per-wave buffer: 2 batches x 2 vectors
constexpr int OFF_WR2 = 8 * BUFW;   // R2 LDS slice (L2 blocks): 64 rows x 66
constexpr int SMEM_BYTES = 84 * 1024;  // > 80KB => exactly 1 block/CU

__device__ __forceinline__ float sigm(float x) { return 1.f / (1.f + expf(-x)); }

__device__ __forceinline__ float aload(const float* p) {
  return __hip_atomic_load(const_cast<float*>(p), __ATOMIC_RELAXED, __HIP_MEMORY_SCOPE_AGENT);
}
__device__ __forceinline__ int aloadi(const int* p) {
  return __hip_atomic_load(const_cast<int*>(p), __ATOMIC_RELAXED, __HIP_MEMORY_SCOPE_AGENT);
}
__device__ __forceinline__ void astore(float* p, float v) {
  __hip_atomic_store(p, v, __ATOMIC_RELAXED, __HIP_MEMORY_SCOPE_AGENT);
}
__device__ __forceinline__ void astorei(int* p, int v) {
  __hip_atomic_store(p, v, __ATOMIC_RELAXED, __HIP_MEMORY_SCOPE_AGENT);
}

// Wait until all 64 per-slice flags (one per lane) reach target. Bounded so a
// logic bug degrades to wrong-but-terminating instead of a hang.
__device__ __forceinline__ bool spin_ge(const int* flags, int lane, int target, bool prev_ok) {
  if (!prev_ok) return false;
  int guard = 0;
  while (true) {
    const int f = aloadi(flags + lane);
    if (__all(f >= target)) break;
    if (++guard > (1 << 20)) return false;
    __builtin_amdgcn_s_sleep(1);
  }
  asm volatile("" ::: "memory");
  return true;
}

__global__ __launch_bounds__(NTHR) void swd_kernel(
    const float* __restrict__ ctx, const float* __restrict__ Wc, const float* __restrict__ bc,
    const float* __restrict__ K1, const float* __restrict__ R1, const float* __restrict__ b1,
    const float* __restrict__ K2, const float* __restrict__ R2, const float* __restrict__ b2,
    const float* __restrict__ Wo, const float* __restrict__ bo,
    float* __restrict__ dout,
    int* __restrict__ flag1, int* __restrict__ flag2,
    float* __restrict__ ring1, float* __restrict__ ring2)
{
  extern __shared__ float sm[];
  const int wgid  = blockIdx.x;
  const int layer = wgid >> 7;        // 0: layer-1 blocks, 1: layer-2 blocks
  const int half  = (wgid >> 6) & 1;  // which 16 batches
  const int slice = wgid & 63;        // unit slice (4 units = 16 gate-cols)
  const int tid  = threadIdx.x;
  const int lane = tid & 63;
  const int wid  = tid >> 6;
  const int c  = lane & 15;           // local z-column
  const int kk = lane >> 4;           // 64-unit reduction chunk
  const int q  = c >> 2;              // gate (i,f,g,o)
  const int u  = c & 3;               // unit within slice
  const int gc = q * UNITS + slice * 4 + u;  // keras gate-major column
  float* buf = sm + wid * BUFW;       // wave-private staging
  bool ok = true;

  if (layer == 0) {
    // ---- weights into VGPRs (~80 floats/thread: no spill at 112) ----
    float w1[64];
    #pragma unroll
    for (int j = 0; j < 64; ++j) w1[j] = R1[(64 * kk + j) * 1024 + gc];
    const float k1a = K1[gc], k1b = K1[1024 + gc], bb1 = b1[gc];
    float wo[8];
    #pragma unroll
    for (int m = 0; m < 4; ++m) {
      wo[2 * m]     = Wo[(4 * lane + m) * 2];
      wo[2 * m + 1] = Wo[(4 * lane + m) * 2 + 1];
    }
    const float bo0 = bo[0], bo1 = bo[1];

    // ---- init: publish H1[0] = relu(ctx @ Wc + bc) slice (ring1 slot 0) ----
    #pragma unroll
    for (int bi = 0; bi < 2; ++bi) {
      const int b = half * 16 + wid * 2 + bi;
      #pragma unroll
      for (int uu = 0; uu < 4; ++uu) {
        float p = 0.f;
        const float* cb = ctx + b * 512;
        const float* wc = Wc + slice * 4 + uu;
        #pragma unroll
        for (int m = 0; m < 8; ++m) {
          const int i = lane * 8 + m;
          p = fmaf(cb[i], wc[i * UNITS], p);
        }
        #pragma unroll
        for (int d = 32; d; d >>= 1) p += __shfl_down(p, d);
        if (lane == 0)
          astore(ring1 + b * UNITS + slice * 4 + uu, fmaxf(p + bc[slice * 4 + uu], 0.f));
      }
      asm volatile("s_waitcnt vmcnt(0)" ::: "memory");
      if (lane == 0) astorei(flag1 + b * NSL + slice, 1);
    }

    float c1a = 0.f, c1b = 0.f;  // cell state (valid on lanes 0-3: unit=lane)
    for (int s = 0; s < TSTEPS; ++s) {
      #pragma unroll
      for (int bi = 0; bi < 2; ++bi) {
        const int b = half * 16 + wid * 2 + bi;
        float& c1 = bi ? c1b : c1a;
        float* bb = buf + bi * 2 * VECF;
        // h1[s]: usually already available (published by L1 peers)
        ok = spin_ge(flag1 + b * NSL, lane, s + 1, ok);
        const float* r1p = ring1 + ((s & 3) * NB + b) * UNITS + lane * 4;
        *(float4*)(bb + kk * CH + 4 * c) =
            make_float4(aload(r1p), aload(r1p + 1), aload(r1p + 2), aload(r1p + 3));
        // h2[s] -> x = out[s-1]
        float x0 = 0.5f, x1 = 0.5f;
        if (s > 0) {
          ok = spin_ge(flag2 + b * NSL, lane, s, ok);
          const float* r2p = ring2 + ((s & 3) * NB + b) * UNITS + lane * 4;
          const float g0 = aload(r2p), g1 = aload(r2p + 1), g2 = aload(r2p + 2), g3 = aload(r2p + 3);
          float po0 = g0 * wo[0] + g1 * wo[2] + g2 * wo[4] + g3 * wo[6];
          float po1 = g0 * wo[1] + g1 * wo[3] + g2 * wo[5] + g3 * wo[7];
          #pragma unroll
          for (int d = 1; d < 64; d <<= 1) { po0 += __shfl_xor(po0, d); po1 += __shfl_xor(po1, d); }
          x0 = sigm(po0 + bo0); x1 = sigm(po1 + bo1);
          if (slice == 0 && lane == 0)
            *(float2*)(dout + (b * TSTEPS + s - 1) * 2) = make_float2(x0, x1);
        }
        // z1 = h1[s] @ R1-slice  (weights in regs; h broadcast-read from LDS)
        float ax = 0.f, ay = 0.f, az = 0.f, aw = 0.f;
        #pragma unroll
        for (int j = 0; j < 16; ++j) {
          const float4 hv = *(const float4*)(bb + kk * CH + 4 * j);
          ax = fmaf(w1[4 * j + 0], hv.x, ax);
          ay = fmaf(w1[4 * j + 1], hv.y, ay);
          az = fmaf(w1[4 * j + 2], hv.z, az);
          aw = fmaf(w1[4 * j + 3], hv.w, aw);
        }
        float part = (ax + ay) + (az + aw);
        part += __shfl_down(part, 16);
        part += __shfl_down(part, 32);
        const float z   = part + x0 * k1a + x1 * k1b + bb1;
        const float act = (q == 2) ? tanhf(z) : sigm(z);
        const float gi = __shfl(act, u),     gf = __shfl(act, 4 + u),
                    gg = __shfl(act, 8 + u), go = __shfl(act, 12 + u);
        if (lane < 4) {
          const float cn = gf * c1 + gi * gg;
          c1 = cn;
          astore(ring1 + (((s + 1) & 3) * NB + b) * UNITS + slice * 4 + lane, go * tanhf(cn));
        }
        asm volatile("s_waitcnt vmcnt(0)" ::: "memory");
        if (lane == 0) astorei(flag1 + b * NSL + slice, s + 2);
      }
    }
    // ---- epilogue: out[T-1] = sigmoid(H2[T] @ Wo + bo), written by slice 0 ----
    if (slice == 0) {
      #pragma unroll
      for (int bi = 0; bi < 2; ++bi) {
        const int b = half * 16 + wid * 2 + bi;
        ok = spin_ge(flag2 + b * NSL, lane, TSTEPS, ok);
        const float* r2p = ring2 + ((TSTEPS & 3) * NB + b) * UNITS + lane * 4;
        const float g0 = aload(r2p), g1 = aload(r2p + 1), g2 = aload(r2p + 2), g3 = aload(r2p + 3);
        float po0 = g0 * wo[0] + g1 * wo[2] + g2 * wo[4] + g3 * wo[6];
        float po1 = g0 * wo[1] + g1 * wo[3] + g2 * wo[5] + g3 * wo[7];
        #pragma unroll
        for (int d = 1; d < 64; d <<= 1) { po0 += __shfl_xor(po0, d); po1 += __shfl_xor(po1, d); }
        if (lane == 0)
          *(float2*)(dout + (b * TSTEPS + TSTEPS - 1) * 2) =
              make_float2(sigm(po0 + bo0), sigm(po1 + bo1));
      }
    }
  } else {
    // ======================= layer-2 blocks =======================
    // K2 slice in VGPRs (64/thread); R2 slice in block-shared LDS (one-time).
    float wk[64];
    #pragma unroll
    for (int j = 0; j < 64; ++j) wk[j] = K2[(64 * kk + j) * 1024 + gc];
    {
      float* wr2 = sm + OFF_WR2;
      for (int e = tid; e < 64 * 64; e += NTHR) {
        const int r = e >> 6, j = e & 63;       // row r = cc*4 + kkk
        const int cc = r >> 2, kkk = r & 3;
        const int gcr = (cc >> 2) * UNITS + slice * 4 + (cc & 3);
        wr2[r * 66 + j] = R2[(64 * kkk + j) * 1024 + gcr];
      }
    }
    __syncthreads();                            // R2 LDS ready (block-uniform branch)
    const float* wrl = sm + OFF_WR2 + (c * 4 + kk) * 66;
    const float bb2 = b2[gc];
    float c2a = 0.f, c2b = 0.f;
    for (int s = 0; s < TSTEPS; ++s) {
      #pragma unroll
      for (int bi = 0; bi < 2; ++bi) {
        const int b = half * 16 + wid * 2 + bi;
        float& c2 = bi ? c2b : c2a;
        float* bh1 = buf + bi * 2 * VECF;
        float* bh2 = bh1 + VECF;
        // h2[s]: published by L2 peers one stage ago (usually ready)
        float g0 = 0.f, g1 = 0.f, g2 = 0.f, g3 = 0.f;
        if (s > 0) {
          ok = spin_ge(flag2 + b * NSL, lane, s, ok);
          const float* r2p = ring2 + ((s & 3) * NB + b) * UNITS + lane * 4;
          g0 = aload(r2p); g1 = aload(r2p + 1); g2 = aload(r2p + 2); g3 = aload(r2p + 3);
        }
        *(float4*)(bh2 + kk * CH + 4 * c) = make_float4(g0, g1, g2, g3);
        // h1[s+1]: the later-arriving dependency
        ok = spin_ge(flag1 + b * NSL, lane, s + 2, ok);
        const float* r1p = ring1 + (((s + 1) & 3) * NB + b) * UNITS + lane * 4;
        *(float4*)(bh1 + kk * CH + 4 * c) =
            make_float4(aload(r1p), aload(r1p + 1), aload(r1p + 2), aload(r1p + 3));
        // z2 = h1[s+1] @ K2-slice (regs) + h2[s] @ R2-slice (LDS)
        float ax = 0.f, ay = 0.f, az = 0.f, aw = 0.f;
        #pragma unroll
        for (int j = 0; j < 16; ++j) {
          const float4 h1v = *(const float4*)(bh1 + kk * CH + 4 * j);
          const float4 h2v = *(const float4*)(bh2 + kk * CH + 4 * j);
          const float4 wv  = *(const float4*)(wrl + 4 * j);
          ax = fmaf(wk[4 * j + 0], h1v.x, ax);
          ay = fmaf(wk[4 * j + 1], h1v.y, ay);
          az = fmaf(wk[4 * j + 2], h1v.z, az);
          aw = fmaf(wk[4 * j + 3], h1v.w, aw);
          ax = fmaf(wv.x, h2v.x, ax);
          ay = fmaf(wv.y, h2v.y, ay);
          az = fmaf(wv.z, h2v.z, az);
          aw = fmaf(wv.w, h2v.w, aw);
        }
        float part = (ax + ay) + (az + aw);
        part += __shfl_down(part, 16);
        part += __shfl_down(part, 32);
        const float z   = part + bb2;
        const float act = (q == 2) ? tanhf(z) : sigm(z);
        const float gi = __shfl(act, u),     gf = __shfl(act, 4 + u),
                    gg = __shfl(act, 8 + u), go = __shfl(act, 12 + u);
        if (lane < 4) {
          const float cn = gf * c2 + gi * gg;
          c2 = cn;
          astore(ring2 + (((s + 1) & 3) * NB + b) * UNITS + slice * 4 + lane, go * tanhf(cn));
        }
        asm volatile("s_waitcnt vmcnt(0)" ::: "memory");
        if (lane == 0) astorei(flag2 + b * NSL + slice, s + 1);
      }
    }
  }
  (void)ok;
}

extern "C" void kernel_launch(void* const* d_in, const int* in_sizes, int n_in,
                              void* d_out, int out_size, void* d_ws, size_t ws_size,
                              hipStream_t stream) {
  (void)in_sizes; (void)n_in; (void)out_size; (void)ws_size;
  const float* ctx = (const float*)d_in[0];
  const float* Wc  = (const float*)d_in[1];
  const float* bc  = (const float*)d_in[2];
  const float* K1  = (const float*)d_in[3];
  const float* R1  = (const float*)d_in[4];
  const float* b1  = (const float*)d_in[5];
  const float* K2  = (const float*)d_in[6];
  const float* R2  = (const float*)d_in[7];
  const float* b2  = (const float*)d_in[8];
  const float* Wo  = (const float*)d_in[9];
  const float* bo  = (const float*)d_in[10];

  char* ws = (char*)d_ws;
  int*   flag1 = (int*)ws;                                   // [NB][NSL]
  int*   flag2 = flag1 + NB * NSL;                           // [NB][NSL]
  float* ring1 = (float*)(ws + 2 * NB * NSL * sizeof(int));  // [4][NB][UNITS]
  float* ring2 = ring1 + 4 * NB * UNITS;                     // [4][NB][UNITS]
  // ws use: 16 KiB flags + 256 KiB rings = 272 KiB

  hipMemsetAsync(d_ws, 0, 2 * NB * NSL * sizeof(int), stream);  // reset flags
  hipFuncSetAttribute((const void*)swd_kernel,
                      hipFuncAttributeMaxDynamicSharedMemorySize, SMEM_BYTES);
  swd_kernel<<<dim3(256), dim3(NTHR), SMEM_BYTES, stream>>>(
      ctx, Wc, bc, K1, R1, b1, K2, R2, b2, Wo, bo,
      (float*)d_out, flag1, flag2, ring1, ring2);
}